// Round 2
// baseline (540.006 us; speedup 1.0000x reference)
//
#include <hip/hip_runtime.h>

// Problem constants (from reference)
#define BATCH    4096
#define TSEQ     64
#define DDIM     250
#define SSTACK   3
#define HDIM     125
#define NT       4
#define NL       50
#define NOUT     (NT + NL)     // 54
#define KDIM     1000          // 4 * DDIM
#define BM       8             // batch rows per block

// Grid: BATCH/BM = 512 blocks x 256 threads.
// Threads 0..124 own hidden column j of the "transitions" MLP, 125..249 of
// "relations". Inner loop: 1 coalesced W1 load + BM block-uniform x loads
// (expected to scalarize to s_load) + BM FMAs. No LDS in the hot loop.
__global__ __launch_bounds__(256, 2) void parser_gemm_kernel(
    const float* __restrict__ lstm_out,      // [B, T, D]
    const int*   __restrict__ stack_index,   // [B, 3]
    const int*   __restrict__ stack_len,     // [B]
    const int*   __restrict__ buffer_index,  // [B, 1]
    const int*   __restrict__ buffer_len,    // [B]
    const float* __restrict__ W1_t,          // [1000, 125]
    const float* __restrict__ b1_t,          // [125]
    const float* __restrict__ W2_t,          // [125, 4]
    const float* __restrict__ b2_t,          // [4]
    const float* __restrict__ W1_r,          // [1000, 125]
    const float* __restrict__ b1_r,          // [125]
    const float* __restrict__ W2_r,          // [125, 50]
    const float* __restrict__ b2_r,          // [50]
    const float* __restrict__ zeropage,      // >= DDIM zeros (in d_ws)
    float* __restrict__ out_trans,           // [B, 4]
    float* __restrict__ out_rel)             // [B, 50]
{
    __shared__ float h_lds[BM][2 * HDIM + 2];   // 250 cols, padded stride

    const int tid = threadIdx.x;
    const int b0  = blockIdx.x * BM;

    const bool is_t   = (tid < HDIM);
    const bool active = (tid < 2 * HDIM);
    const int  j      = is_t ? tid : (tid - HDIM);
    const float* __restrict__ W1 = is_t ? W1_t : W1_r;
    // inactive threads read column 0 harmlessly (never stored)
    const int jcol = active ? j : 0;

    float acc[BM];
    #pragma unroll
    for (int m = 0; m < BM; ++m) acc[m] = 0.0f;

    for (int s = 0; s < 4; ++s) {
        // block-uniform per-row source pointers (masked slots -> zero page)
        const float* p[BM];
        #pragma unroll
        for (int m = 0; m < BM; ++m) {
            const int b = b0 + m;
            int  idx;
            bool valid;
            if (s < SSTACK) {
                idx   = stack_index[b * SSTACK + s];
                valid = (s < stack_len[b]);
            } else {
                idx   = buffer_index[b];
                valid = (buffer_len[b] > 0);
            }
            p[m] = valid ? (lstm_out + ((size_t)b * TSEQ + (size_t)idx) * DDIM)
                         : zeropage;
        }
        const float* __restrict__ Wp = W1 + (size_t)(s * DDIM) * HDIM + jcol;
        #pragma unroll 4
        for (int d = 0; d < DDIM; ++d) {
            const float w = Wp[(size_t)d * HDIM];
            #pragma unroll
            for (int m = 0; m < BM; ++m) {
                acc[m] = fmaf(p[m][d], w, acc[m]);
            }
        }
    }

    // hidden activations -> LDS
    if (active) {
        const float bias = is_t ? b1_t[j] : b1_r[j];
        #pragma unroll
        for (int m = 0; m < BM; ++m) {
            h_lds[m][tid] = tanhf(acc[m] + bias);
        }
    }
    __syncthreads();

    // second layer + final tanh: BM * 54 = 432 outputs
    for (int t = tid; t < BM * NOUT; t += 256) {
        const int m = t / NOUT;
        const int o = t - m * NOUT;
        float a = 0.0f;
        if (o < NT) {
            #pragma unroll 5
            for (int k = 0; k < HDIM; ++k) {
                a = fmaf(h_lds[m][k], W2_t[k * NT + o], a);
            }
            out_trans[(size_t)(b0 + m) * NT + o] = tanhf(a + b2_t[o]);
        } else {
            const int r = o - NT;
            #pragma unroll 5
            for (int k = 0; k < HDIM; ++k) {
                a = fmaf(h_lds[m][HDIM + k], W2_r[k * NL + r], a);
            }
            out_rel[(size_t)(b0 + m) * NL + r] = tanhf(a + b2_r[r]);
        }
    }
}

extern "C" void kernel_launch(void* const* d_in, const int* in_sizes, int n_in,
                              void* d_out, int out_size, void* d_ws, size_t ws_size,
                              hipStream_t stream) {
    const float* lstm_out     = (const float*)d_in[0];
    const int*   stack_index  = (const int*)  d_in[1];
    const int*   stack_len    = (const int*)  d_in[2];
    const int*   buffer_index = (const int*)  d_in[3];
    const int*   buffer_len   = (const int*)  d_in[4];
    const float* W1_t = (const float*)d_in[5];
    const float* b1_t = (const float*)d_in[6];
    const float* W2_t = (const float*)d_in[7];
    const float* b2_t = (const float*)d_in[8];
    const float* W1_r = (const float*)d_in[9];
    const float* b1_r = (const float*)d_in[10];
    const float* W2_r = (const float*)d_in[11];
    const float* b2_r = (const float*)d_in[12];

    float* out_trans = (float*)d_out;                           // [4096, 4]
    float* out_rel   = (float*)d_out + (size_t)BATCH * NT;      // [4096, 50]

    // zero page for masked gather slots (ws is re-poisoned before every launch)
    float* zeropage = (float*)d_ws;
    hipMemsetAsync(zeropage, 0, DDIM * sizeof(float), stream);

    parser_gemm_kernel<<<BATCH / BM, 256, 0, stream>>>(
        lstm_out, stack_index, stack_len, buffer_index, buffer_len,
        W1_t, b1_t, W2_t, b2_t, W1_r, b1_r, W2_r, b2_r,
        zeropage, out_trans, out_rel);
}

// Round 3
// 394.782 us; speedup vs baseline: 1.3679x; 1.3679x over previous
//
#include <hip/hip_runtime.h>

#define BATCH 4096
#define TSEQ  64
#define DDIM  250
#define HDIM  125
#define NT    4
#define NL    50
#define KP    1024     // padded K (1000 real)
#define NP    256      // padded N (250 real: 0..124 = t-hidden, 125..249 = r-hidden)

typedef __attribute__((ext_vector_type(8))) __bf16 bf16x8;
typedef __attribute__((ext_vector_type(4))) float  f32x4;

__device__ __forceinline__ unsigned short f32_to_bf16(float f) {
    unsigned int u = __float_as_uint(f);
    u += 0x7FFFu + ((u >> 16) & 1u);          // round-to-nearest-even
    return (unsigned short)(u >> 16);
}

// ---------------- prep: gather+mask X -> bf16 [4096][1024]; W^T cat -> bf16 [256][1024]
__global__ __launch_bounds__(256) void prep_kernel(
    const float* __restrict__ lstm_out,
    const int*   __restrict__ stack_index,
    const int*   __restrict__ stack_len,
    const int*   __restrict__ buffer_index,
    const int*   __restrict__ buffer_len,
    const float* __restrict__ W1_t,
    const float* __restrict__ W1_r,
    unsigned short* __restrict__ Xb,
    unsigned short* __restrict__ Wb)
{
    const int blk = blockIdx.x;
    const int t   = threadIdx.x;

    if (blk < BATCH) {
        const int b    = blk;
        const int slen = stack_len[b];
        const int blen = buffer_len[b];
        const int idxB = buffer_index[b];
        const int k0   = t * 4;
        unsigned short v[4];
        #pragma unroll
        for (int i = 0; i < 4; ++i) {
            const int k = k0 + i;
            float f = 0.0f;
            if (k < 1000) {
                const int s = k / 250;
                const int d = k - s * 250;
                const int idxS = stack_index[b * 3 + (s < 3 ? s : 2)]; // always in-bounds
                const int idx  = (s < 3) ? idxS : idxB;
                const bool valid = (s < 3) ? (s < slen) : (blen > 0);
                if (valid) f = lstm_out[((size_t)b * TSEQ + (size_t)idx) * DDIM + d];
            }
            v[i] = f32_to_bf16(f);
        }
        *reinterpret_cast<ushort4*>(Xb + (size_t)b * KP + k0) =
            make_ushort4(v[0], v[1], v[2], v[3]);
    } else {
        const int n  = blk - BATCH;            // 0..255 (Wb row = output col)
        const int k0 = t * 4;
        unsigned short v[4];
        #pragma unroll
        for (int i = 0; i < 4; ++i) {
            const int k = k0 + i;
            float f = 0.0f;
            if (k < 1000 && n < 250) {
                f = (n < HDIM) ? W1_t[(size_t)k * HDIM + n]
                               : W1_r[(size_t)k * HDIM + (n - HDIM)];
            }
            v[i] = f32_to_bf16(f);
        }
        *reinterpret_cast<ushort4*>(Wb + (size_t)n * KP + k0) =
            make_ushort4(v[0], v[1], v[2], v[3]);
    }
}

// ---------------- GEMM (BM=16 rows/block, all 256 cols) + fused MLP epilogue
__global__ __launch_bounds__(256) void gemm_kernel(
    const unsigned short* __restrict__ Xb,
    const unsigned short* __restrict__ Wb,
    const float* __restrict__ b1_t,
    const float* __restrict__ b1_r,
    const float* __restrict__ W2_t,
    const float* __restrict__ b2_t,
    const float* __restrict__ W2_r,
    const float* __restrict__ b2_r,
    float* __restrict__ out_trans,
    float* __restrict__ out_rel)
{
    __shared__ __align__(16) unsigned char XsRaw[16 * 2048]; // 16 rows x 1024 bf16, XOR-swizzled
    __shared__ float h_lds[16][260];  // cols 0..124 = h_t, 128..252 = h_r (aligned b128 reads)

    const int tid = threadIdx.x;
    const int b0  = blockIdx.x * 16;

    // ---- stage full X-panel into LDS (swizzled: byte ^= (row&7)<<4)
    #pragma unroll
    for (int i = 0; i < 8; ++i) {
        const int chunk = i * 256 + tid;      // 0..2047 = 16 rows x 128 chunks of 16B
        const int row   = chunk >> 7;
        const int c     = chunk & 127;
        uint4 g = *reinterpret_cast<const uint4*>(Xb + (size_t)(b0 + row) * KP + c * 8);
        const int byte = row * 2048 + ((c * 16) ^ ((row & 7) << 4));
        *reinterpret_cast<uint4*>(XsRaw + byte) = g;
    }
    __syncthreads();

    const int lane  = tid & 63;
    const int wave  = tid >> 6;
    const int lrow  = lane & 15;              // A row / B col within fragment
    const int lk    = (lane >> 4) * 8;        // k offset within a 32-chunk
    const int nbase = wave * 64;

    f32x4 acc0 = {0.f,0.f,0.f,0.f}, acc1 = acc0, acc2 = acc0, acc3 = acc0;

    const unsigned short* wbase = Wb + (size_t)(nbase + lrow) * KP + lk;
    const unsigned char*  xrow  = XsRaw + lrow * 2048;
    const int xmask = (lrow & 7) << 4;

    #pragma unroll 8
    for (int ks = 0; ks < 32; ++ks) {
        const int xbyte = ((ks * 32 + lk) * 2) ^ xmask;
        bf16x8 a   = *reinterpret_cast<const bf16x8*>(xrow + xbyte);
        bf16x8 bv0 = *reinterpret_cast<const bf16x8*>(wbase + 0 * 16 * KP + ks * 32);
        bf16x8 bv1 = *reinterpret_cast<const bf16x8*>(wbase + 1 * 16 * KP + ks * 32);
        bf16x8 bv2 = *reinterpret_cast<const bf16x8*>(wbase + 2 * 16 * KP + ks * 32);
        bf16x8 bv3 = *reinterpret_cast<const bf16x8*>(wbase + 3 * 16 * KP + ks * 32);
        acc0 = __builtin_amdgcn_mfma_f32_16x16x32_bf16(a, bv0, acc0, 0, 0, 0);
        acc1 = __builtin_amdgcn_mfma_f32_16x16x32_bf16(a, bv1, acc1, 0, 0, 0);
        acc2 = __builtin_amdgcn_mfma_f32_16x16x32_bf16(a, bv2, acc2, 0, 0, 0);
        acc3 = __builtin_amdgcn_mfma_f32_16x16x32_bf16(a, bv3, acc3, 0, 0, 0);
    }

    // ---- hidden activation: C/D layout col=lane&15, row=(lane>>4)*4+reg (m89)
    {
        const int r0 = (lane >> 4) * 4;
        #pragma unroll
        for (int fn = 0; fn < 4; ++fn) {
            const f32x4 ac = (fn == 0) ? acc0 : (fn == 1) ? acc1 : (fn == 2) ? acc2 : acc3;
            const int col = nbase + fn * 16 + lrow;
            const float bias = (col < HDIM) ? b1_t[col]
                             : (col < 250)  ? b1_r[col - HDIM] : 0.0f;
            #pragma unroll
            for (int rg = 0; rg < 4; ++rg) {
                const float v = tanhf(ac[rg] + bias);
                if (col < HDIM)      h_lds[r0 + rg][col] = v;
                else if (col < 250)  h_lds[r0 + rg][col + 3] = v;   // rel re-based to 128
            }
        }
    }
    __syncthreads();

    // ---- second layer + final tanh: thread = (m = tid&15, out-group og = tid>>4)
    const int m  = tid & 15;
    const int og = tid >> 4;
    if (og < 14) {                       // og 0 -> 4 trans outs; og 1..13 -> 4 rel outs
        const bool isT = (og == 0);
        const int  base = isT ? 0 : 128;
        const int  r0   = isT ? 0 : (og - 1) * 4;
        const int  ldw  = isT ? NT : NL;
        const float* __restrict__ W2 = isT ? W2_t : W2_r;
        const float* __restrict__ b2 = isT ? b2_t : b2_r;
        float a0 = 0.f, a1 = 0.f, a2 = 0.f, a3 = 0.f;
        #pragma unroll 4
        for (int k = 0; k < HDIM; ++k) {
            const float h = h_lds[m][base + k];
            const float* w = W2 + (size_t)k * ldw + r0;
            a0 = fmaf(h, w[0], a0);
            if (r0 + 1 < ldw) a1 = fmaf(h, w[1], a1);
            if (r0 + 2 < ldw) a2 = fmaf(h, w[2], a2);
            if (r0 + 3 < ldw) a3 = fmaf(h, w[3], a3);
        }
        float* outp = isT ? (out_trans + (size_t)(b0 + m) * NT)
                          : (out_rel   + (size_t)(b0 + m) * NL);
        if (r0 + 0 < ldw) outp[r0 + 0] = tanhf(a0 + b2[r0 + 0]);
        if (r0 + 1 < ldw) outp[r0 + 1] = tanhf(a1 + b2[r0 + 1]);
        if (r0 + 2 < ldw) outp[r0 + 2] = tanhf(a2 + b2[r0 + 2]);
        if (r0 + 3 < ldw) outp[r0 + 3] = tanhf(a3 + b2[r0 + 3]);
    }
}

extern "C" void kernel_launch(void* const* d_in, const int* in_sizes, int n_in,
                              void* d_out, int out_size, void* d_ws, size_t ws_size,
                              hipStream_t stream) {
    const float* lstm_out     = (const float*)d_in[0];
    const int*   stack_index  = (const int*)  d_in[1];
    const int*   stack_len    = (const int*)  d_in[2];
    const int*   buffer_index = (const int*)  d_in[3];
    const int*   buffer_len   = (const int*)  d_in[4];
    const float* W1_t = (const float*)d_in[5];
    const float* b1_t = (const float*)d_in[6];
    const float* W2_t = (const float*)d_in[7];
    const float* b2_t = (const float*)d_in[8];
    const float* W1_r = (const float*)d_in[9];
    const float* b1_r = (const float*)d_in[10];
    const float* W2_r = (const float*)d_in[11];
    const float* b2_r = (const float*)d_in[12];

    float* out_trans = (float*)d_out;                       // [4096, 4]
    float* out_rel   = (float*)d_out + (size_t)BATCH * NT;  // [4096, 50]

    unsigned short* Wb = (unsigned short*)d_ws;             // [256][1024] bf16
    unsigned short* Xb = Wb + (size_t)NP * KP;              // [4096][1024] bf16

    prep_kernel<<<BATCH + NP, 256, 0, stream>>>(
        lstm_out, stack_index, stack_len, buffer_index, buffer_len,
        W1_t, W1_r, Xb, Wb);

    gemm_kernel<<<BATCH / 16, 256, 0, stream>>>(
        Xb, Wb, b1_t, b1_r, W2_t, b2_t, W2_r, b2_r, out_trans, out_rel);
}

// Round 4
// 384.832 us; speedup vs baseline: 1.4032x; 1.0259x over previous
//
#include <hip/hip_runtime.h>

#define BATCH 4096
#define TSEQ  64
#define DDIM  250
#define HDIM  125
#define NT    4
#define NL    50
#define KP    1024     // padded K (1000 real)
#define KREAL 1000

typedef __attribute__((ext_vector_type(8))) __bf16 bf16x8;
typedef __attribute__((ext_vector_type(4))) float  f32x4;

__device__ __forceinline__ unsigned short f32_to_bf16(float f) {
    unsigned int u = __float_as_uint(f);
    u += 0x7FFFu + ((u >> 16) & 1u);          // round-to-nearest-even
    return (unsigned short)(u >> 16);
}

// ---------------- W prep: pack concat(W1_t,W1_r)^T into MFMA B-fragment order.
// Wfrag[f][ks][lane][j] (f<16 col-group, ks<32 k-step, lane<64, j<8):
//   col = f*16 + (lane&15);  k = ks*32 + (lane>>4)*8 + j
// so the GEMM's per-wave B-load is 64 lanes x 16B contiguous (1 KB).
__global__ __launch_bounds__(256) void prep_w_kernel(
    const float* __restrict__ W1_t,
    const float* __restrict__ W1_r,
    unsigned short* __restrict__ Wfrag)
{
    const int g    = blockIdx.x * 256 + threadIdx.x;   // 0..32767
    const int f    = g >> 11;                          // 2048 chunks per frag
    const int rem  = g & 2047;
    const int ks   = rem >> 6;
    const int lane = rem & 63;
    const int col  = f * 16 + (lane & 15);
    const int kb   = ks * 32 + (lane >> 4) * 8;
    unsigned short v[8];
    #pragma unroll
    for (int j = 0; j < 8; ++j) {
        const int k = kb + j;
        float x = 0.0f;
        if (k < KREAL && col < 250) {
            x = (col < HDIM) ? W1_t[(size_t)k * HDIM + col]
                             : W1_r[(size_t)k * HDIM + (col - HDIM)];
        }
        v[j] = f32_to_bf16(x);
    }
    *reinterpret_cast<ushort4*>(Wfrag + (size_t)g * 8)     = make_ushort4(v[0],v[1],v[2],v[3]);
    *reinterpret_cast<ushort4*>(Wfrag + (size_t)g * 8 + 4) = make_ushort4(v[4],v[5],v[6],v[7]);
}

// ---------------- fused gather + GEMM + 2-layer MLP epilogue.
// 256 blocks (1/CU) x 512 threads (8 waves = 2/SIMD). BM=16 batch rows/block,
// all 256 (padded) hidden cols; wave w owns col-groups f0=2w, f1=2w+1.
__global__ __launch_bounds__(512) void fused_kernel(
    const float* __restrict__ lstm_out,
    const int*   __restrict__ stack_index,
    const int*   __restrict__ stack_len,
    const int*   __restrict__ buffer_index,
    const int*   __restrict__ buffer_len,
    const unsigned short* __restrict__ Wfrag,
    const float* __restrict__ b1_t,
    const float* __restrict__ b1_r,
    const float* __restrict__ W2_t,
    const float* __restrict__ b2_t,
    const float* __restrict__ W2_r,
    const float* __restrict__ b2_r,
    float* __restrict__ out_trans,
    float* __restrict__ out_rel)
{
    __shared__ __align__(16) unsigned char Xs[16 * 2048]; // 16 rows x 1024 bf16, XOR-swizzled
    __shared__ float h_lds[16][260];   // 0..124 = h_t; 128..252 = h_r (re-based)

    const int tid  = threadIdx.x;
    const int wave = tid >> 6;
    const int lane = tid & 63;
    const int b0   = blockIdx.x * 16;

    // ---- gather + mask + bf16-convert straight into swizzled LDS.
    // 64 (row m, slot s) pairs; wave w handles pairs 8w..8w+7 (uniform idx -> s_load).
    #pragma unroll
    for (int i = 0; i < 8; ++i) {
        const int pair = wave * 8 + i;
        const int m = pair >> 2;
        const int s = pair & 3;
        const int b = b0 + m;
        int idx; bool valid;
        if (s < 3) { idx = stack_index[b * 3 + s]; valid = (s < stack_len[b]); }
        else       { idx = buffer_index[b];        valid = (buffer_len[b] > 0); }
        const float* __restrict__ src = lstm_out + ((size_t)b * TSEQ + (size_t)idx) * DDIM;
        const int colbase = s * 250;
        const int xm = (m & 7) << 4;
        #pragma unroll
        for (int d0 = 0; d0 < 256; d0 += 64) {
            const int d = d0 + lane;
            if (d < 250) {
                const float x = valid ? src[d] : 0.0f;
                const int byte = m * 2048 + (((colbase + d) * 2) ^ xm);
                *reinterpret_cast<unsigned short*>(Xs + byte) = f32_to_bf16(x);
            }
        }
    }
    // zero-fill padded cols 1000..1023
    if (tid < 384) {
        const int m = tid / 24;
        const int c = tid - m * 24;
        const int byte = m * 2048 + (((1000 + c) * 2) ^ ((m & 7) << 4));
        *reinterpret_cast<unsigned short*>(Xs + byte) = 0;
    }
    __syncthreads();

    // ---- MFMA: per wave 2 col-frags x 32 k-steps
    const int lrow  = lane & 15;
    const int lk    = (lane >> 4) * 8;
    const int xmask = (lrow & 7) << 4;
    const unsigned char* xrow = Xs + lrow * 2048;

    f32x4 acc0 = {0.f,0.f,0.f,0.f}, acc1 = acc0;
    const unsigned short* wb0 = Wfrag + ((size_t)(wave * 2 + 0) * 2048 + lane) * 8;
    const unsigned short* wb1 = Wfrag + ((size_t)(wave * 2 + 1) * 2048 + lane) * 8;

    #pragma unroll 8
    for (int ks = 0; ks < 32; ++ks) {
        bf16x8 a   = *reinterpret_cast<const bf16x8*>(xrow + (((ks * 32 + lk) * 2) ^ xmask));
        bf16x8 bv0 = *reinterpret_cast<const bf16x8*>(wb0 + ks * 512);
        bf16x8 bv1 = *reinterpret_cast<const bf16x8*>(wb1 + ks * 512);
        acc0 = __builtin_amdgcn_mfma_f32_16x16x32_bf16(a, bv0, acc0, 0, 0, 0);
        acc1 = __builtin_amdgcn_mfma_f32_16x16x32_bf16(a, bv1, acc1, 0, 0, 0);
    }

    // ---- hidden activation: C/D layout col=lane&15, row=(lane>>4)*4+reg (m89)
    {
        const int r0 = (lane >> 4) * 4;
        #pragma unroll
        for (int fn = 0; fn < 2; ++fn) {
            const f32x4 ac = fn ? acc1 : acc0;
            const int col = (wave * 2 + fn) * 16 + lrow;
            const float bias = (col < HDIM) ? b1_t[col]
                             : (col < 250)  ? b1_r[col - HDIM] : 0.0f;
            #pragma unroll
            for (int rg = 0; rg < 4; ++rg) {
                const float v = tanhf(ac[rg] + bias);
                if (col < HDIM)     h_lds[r0 + rg][col] = v;
                else if (col < 250) h_lds[r0 + rg][col + 3] = v;
            }
        }
    }
    __syncthreads();

    // ---- second layer + final tanh: m = tid&15, out-group og = tid>>4
    const int m  = tid & 15;
    const int og = tid >> 4;
    if (og < 14) {                       // og 0 -> 4 trans outs; 1..13 -> 4 rel outs
        const bool isT = (og == 0);
        const int  base = isT ? 0 : 128;
        const int  r0   = isT ? 0 : (og - 1) * 4;
        const int  ldw  = isT ? NT : NL;
        const float* __restrict__ W2 = isT ? W2_t : W2_r;
        const float* __restrict__ b2 = isT ? b2_t : b2_r;
        float a0 = 0.f, a1 = 0.f, a2 = 0.f, a3 = 0.f;
        #pragma unroll 5
        for (int k = 0; k < HDIM; ++k) {
            const float h = h_lds[m][base + k];
            const float* w = W2 + (size_t)k * ldw + r0;
            a0 = fmaf(h, w[0], a0);
            if (r0 + 1 < ldw) a1 = fmaf(h, w[1], a1);
            if (r0 + 2 < ldw) a2 = fmaf(h, w[2], a2);
            if (r0 + 3 < ldw) a3 = fmaf(h, w[3], a3);
        }
        float* outp = isT ? (out_trans + (size_t)(b0 + m) * NT)
                          : (out_rel   + (size_t)(b0 + m) * NL);
        if (r0 + 0 < ldw) outp[r0 + 0] = tanhf(a0 + b2[r0 + 0]);
        if (r0 + 1 < ldw) outp[r0 + 1] = tanhf(a1 + b2[r0 + 1]);
        if (r0 + 2 < ldw) outp[r0 + 2] = tanhf(a2 + b2[r0 + 2]);
        if (r0 + 3 < ldw) outp[r0 + 3] = tanhf(a3 + b2[r0 + 3]);
    }
}

extern "C" void kernel_launch(void* const* d_in, const int* in_sizes, int n_in,
                              void* d_out, int out_size, void* d_ws, size_t ws_size,
                              hipStream_t stream) {
    const float* lstm_out     = (const float*)d_in[0];
    const int*   stack_index  = (const int*)  d_in[1];
    const int*   stack_len    = (const int*)  d_in[2];
    const int*   buffer_index = (const int*)  d_in[3];
    const int*   buffer_len   = (const int*)  d_in[4];
    const float* W1_t = (const float*)d_in[5];
    const float* b1_t = (const float*)d_in[6];
    const float* W2_t = (const float*)d_in[7];
    const float* b2_t = (const float*)d_in[8];
    const float* W1_r = (const float*)d_in[9];
    const float* b1_r = (const float*)d_in[10];
    const float* W2_r = (const float*)d_in[11];
    const float* b2_r = (const float*)d_in[12];

    float* out_trans = (float*)d_out;                       // [4096, 4]
    float* out_rel   = (float*)d_out + (size_t)BATCH * NT;  // [4096, 50]

    unsigned short* Wfrag = (unsigned short*)d_ws;          // 512 KB bf16, frag-ordered

    prep_w_kernel<<<128, 256, 0, stream>>>(W1_t, W1_r, Wfrag);

    fused_kernel<<<BATCH / 16, 512, 0, stream>>>(
        lstm_out, stack_index, stack_len, buffer_index, buffer_len,
        Wfrag, b1_t, b1_r, W2_t, b2_t, W2_r, b2_r, out_trans, out_rel);
}